// Round 14
// baseline (453.988 us; speedup 1.0000x reference)
//
#include <hip/hip_runtime.h>
#include <math.h>

#define BATCH 64
#define HW 56
#define CDIM 96
#define NHEADS 3
#define WSZ 7
#define NTOK 49
#define SHIFT_ 3
#define NWIN_TOT 4096
#define HID 384
#define NTOKENS (BATCH * HW * HW)   // 200704
#define LN100 4.6051702f

typedef __attribute__((ext_vector_type(8))) short bf16x8;
typedef __attribute__((ext_vector_type(8))) _Float16 f16x8;
typedef __attribute__((ext_vector_type(4))) float f32x4;

__device__ inline f32x4 mfma16(bf16x8 a, bf16x8 b, f32x4 c) {
  return __builtin_amdgcn_mfma_f32_16x16x32_bf16(a, b, c, 0, 0, 0);
}
__device__ inline f32x4 mfma16h(f16x8 a, f16x8 b, f32x4 c) {
  return __builtin_amdgcn_mfma_f32_16x16x32_f16(a, b, c, 0, 0, 0);
}

// ---------- bf16/f16 helpers ----------
__device__ inline unsigned short f2b(float f) {
  unsigned u = __float_as_uint(f);
  unsigned r = (u + 0x7FFFu + ((u >> 16) & 1u)) >> 16;
  return (unsigned short)r;
}
__device__ inline float blo(unsigned u) { return __uint_as_float(u << 16); }
__device__ inline float bhi(unsigned u) { return __uint_as_float(u & 0xFFFF0000u); }
__device__ inline unsigned packb(float a, float b) {
  return (unsigned)f2b(a) | ((unsigned)f2b(b) << 16);
}
__device__ inline unsigned packh(float a, float b) {
  _Float16 ha = (_Float16)a, hb = (_Float16)b;
  unsigned short ua = *(unsigned short*)&ha, ub = *(unsigned short*)&hb;
  return (unsigned)ua | ((unsigned)ub << 16);
}
__device__ inline bf16x8 mk8(unsigned d0, unsigned d1, unsigned d2, unsigned d3) {
  union { unsigned u[4]; bf16x8 v; } c;
  c.u[0] = d0; c.u[1] = d1; c.u[2] = d2; c.u[3] = d3;
  return c.v;
}
// GELU with A&S 7.1.26 erf (max abs err 1.5e-7)
__device__ inline float gelu_f(float v) {
  float a = fabsf(v) * 0.70710678118654752f;
  float t = 1.0f / fmaf(a, 0.3275911f, 1.0f);
  float p = t * fmaf(t, fmaf(t, fmaf(t, fmaf(t, 1.061405429f, -1.453152027f),
                                     1.421413741f), -0.284496736f), 0.254829592f);
  float er = 1.0f - p * __expf(-a * a);
  er = (v < 0.f) ? -er : er;
  return 0.5f * v * (1.0f + er);
}

// ---------------- P0: weight conversion into MFMA B-frag layouts --------------
__global__ __launch_bounds__(256) void wconv2_kernel(
    const float* __restrict__ qkv_w, const float* __restrict__ fc1_w,
    const float* __restrict__ fc2_w, const float* __restrict__ proj_w,
    unsigned* __restrict__ qkvf, unsigned* __restrict__ w1f,
    unsigned* __restrict__ w2f, unsigned* __restrict__ pwf) {
  int T = blockIdx.x * 256 + threadIdx.x;
  if (T < 3456) {  // qkv: 18 n-tiles x 3 k-steps
    int tk = T >> 6, l = T & 63;
    int n = tk / 3, ks = tk - n * 3;
    int o = n * 16 + (l & 15);
    const float* src = qkv_w + o * 96 + ks * 32 + (l >> 4) * 8;
    uint4 d;
    d.x = packb(src[0], src[1]); d.y = packb(src[2], src[3]);
    d.z = packb(src[4], src[5]); d.w = packb(src[6], src[7]);
    *(uint4*)&qkvf[(size_t)(tk * 64 + l) * 4] = d;
    return;
  }
  T -= 3456;
  if (T < 4608) {  // fc1
    int tk = T >> 6, l = T & 63;
    int n = tk / 3, ks = tk - n * 3;
    int o = n * 16 + (l & 15);
    const float* src = fc1_w + o * 96 + ks * 32 + (l >> 4) * 8;
    uint4 d;
    d.x = packb(src[0], src[1]); d.y = packb(src[2], src[3]);
    d.z = packb(src[4], src[5]); d.w = packb(src[6], src[7]);
    *(uint4*)&w1f[(size_t)(tk * 64 + l) * 4] = d;
    return;
  }
  T -= 4608;
  if (T < 4608) {  // fc2
    int tk = T >> 6, l = T & 63;
    int n = tk / 12, ks = tk - n * 12;
    int o = n * 16 + (l & 15);
    const float* src = fc2_w + o * 384 + ks * 32 + (l >> 4) * 8;
    uint4 d;
    d.x = packb(src[0], src[1]); d.y = packb(src[2], src[3]);
    d.z = packb(src[4], src[5]); d.w = packb(src[6], src[7]);
    *(uint4*)&w2f[(size_t)(tk * 64 + l) * 4] = d;
    return;
  }
  T -= 4608;
  if (T < 1152) {  // proj
    int tk = T >> 6, l = T & 63;
    int n = tk / 3, ks = tk - n * 3;
    int o = n * 16 + (l & 15);
    const float* src = proj_w + o * 96 + ks * 32 + (l >> 4) * 8;
    uint4 d;
    d.x = packb(src[0], src[1]); d.y = packb(src[2], src[3]);
    d.z = packb(src[4], src[5]); d.w = packb(src[6], src[7]);
    *(uint4*)&pwf[(size_t)(tk * 64 + l) * 4] = d;
  }
}

// ---------------- P1: CPB MLP table raw (169 x 3) -----------------------------
__global__ __launch_bounds__(512) void cpb_table_kernel(
    const float* __restrict__ w1, const float* __restrict__ b1,
    const float* __restrict__ w2, float* __restrict__ tabout) {
  int tid = threadIdx.x;
  if (tid >= 169 * 3) return;
  int e = tid / 3, h = tid - e * 3;
  int i = e / 13, j = e - i * 13;
  float ti = (float)(i - 6) * (8.0f / 6.0f);
  float tj = (float)(j - 6) * (8.0f / 6.0f);
  float sx = (ti > 0.f) ? 1.f : (ti < 0.f ? -1.f : 0.f);
  float sy = (tj > 0.f) ? 1.f : (tj < 0.f ? -1.f : 0.f);
  float tx = sx * log2f(fabsf(ti) + 1.f) * (1.0f / 3.0f);
  float ty = sy * log2f(fabsf(tj) + 1.f) * (1.0f / 3.0f);
  float acc = 0.f;
  for (int jj = 0; jj < 512; ++jj) {
    float hv = tx * w1[jj * 2 + 0] + ty * w1[jj * 2 + 1] + b1[jj];
    float g = 0.5f * hv * (1.f + erff(hv * 0.70710678118654752f));
    acc += g * w2[h * 512 + jj];
  }
  tabout[e * 3 + h] = acc;
}

// ---------------- P2: combined 16*sigmoid(rpb) + shift-mask table -------------
__global__ __launch_bounds__(256) void bm_kernel(
    const float* __restrict__ tabout, const float* __restrict__ mask,
    float* __restrict__ bmtab) {
  int idx = blockIdx.x * 256 + threadIdx.x;
  if (idx >= 64 * NHEADS * NTOK * NTOK) return;
  int wi = idx / (NHEADS * 2401);
  int rem = idx - wi * (NHEADS * 2401);
  int h = rem / 2401, ij = rem - h * 2401;
  int i = ij / NTOK, j = ij - i * NTOK;
  int ri = (i / WSZ) - (j / WSZ) + 6;
  int ci = (i % WSZ) - (j % WSZ) + 6;
  int e = ri * 13 + ci;
  float v = tabout[e * 3 + h];
  bmtab[idx] = 16.f / (1.f + expf(-v)) + mask[(size_t)wi * 2401 + ij];
}

// ---------------- K1: token-major QKV GEMM (MFMA) + cosine norm ---------------
// Output layout: WINDOW-MAJOR [win][h][t][16 dw] so attn reads are coalesced.
__global__ __launch_bounds__(256) void qkv_mfma_kernel(
    const float* __restrict__ x, const unsigned* __restrict__ qkvf,
    const float* __restrict__ q_bias, const float* __restrict__ v_bias,
    const float* __restrict__ logit_scale,
    unsigned* __restrict__ qws, unsigned* __restrict__ kws,
    unsigned* __restrict__ vws) {
  __shared__ unsigned xa[64 * 52];
  int tid = threadIdx.x, lane = tid & 63, wv = tid >> 6;
  size_t tok0 = (size_t)blockIdx.x * 64;

  for (int idx = tid; idx < 3072; idx += 256) {
    int t = idx / 48, c2 = idx - t * 48;
    const float2 s = *(const float2*)(x + (tok0 + t) * 96 + c2 * 2);
    xa[t * 52 + c2] = packb(s.x, s.y);
  }
  __syncthreads();

  int c15 = lane & 15, q4 = lane >> 4;
  bf16x8 afr[3];
  #pragma unroll
  for (int k = 0; k < 3; ++k)
    afr[k] = *(const bf16x8*)&xa[(wv * 16 + c15) * 52 + k * 16 + q4 * 4];

  f32x4 acc[18];
  #pragma unroll
  for (int n = 0; n < 18; ++n) acc[n] = f32x4{0.f, 0.f, 0.f, 0.f};
  #pragma unroll
  for (int n = 0; n < 18; ++n) {
    #pragma unroll
    for (int k = 0; k < 3; ++k) {
      bf16x8 b = *(const bf16x8*)&qkvf[(size_t)((n * 3 + k) * 64 + lane) * 4];
      acc[n] = mfma16(afr[k], b, acc[n]);
    }
  }

  // window-major destination base for each of my 4 tokens
  int tokr0 = (int)tok0 + wv * 16 + q4 * 4;
  int wbase[4];
  #pragma unroll
  for (int i = 0; i < 4; ++i) {
    int tk = tokr0 + i;
    int bb = tk / 3136, rem = tk - bb * 3136;
    int R = rem / 56, C = rem - R * 56;
    int rr = R + 53; if (rr >= 56) rr -= 56;    // rolled row
    int cc = C + 53; if (cc >= 56) cc -= 56;    // rolled col
    int wr = rr / 7, tr2 = rr - wr * 7;
    int wc = cc / 7, tc2 = cc - wc * 7;
    wbase[i] = (bb * 64 + wr * 8 + wc) * 2352 + (tr2 * 7 + tc2) * 16;
  }

  #pragma unroll
  for (int h = 0; h < 3; ++h) {
    float sc = expf(fminf(logit_scale[h], LN100));
    {   // q
      f32x4 a0 = acc[2 * h], a1 = acc[2 * h + 1];
      float b0 = q_bias[h * 32 + c15], b1 = q_bias[h * 32 + 16 + c15];
      unsigned pk[8];
      #pragma unroll
      for (int i = 0; i < 4; ++i) {
        float va = a0[i] + b0, vb = a1[i] + b1;
        float ss = va * va + vb * vb;
        ss += __shfl_xor(ss, 1, 64); ss += __shfl_xor(ss, 2, 64);
        ss += __shfl_xor(ss, 4, 64); ss += __shfl_xor(ss, 8, 64);
        float inv = sc / fmaxf(sqrtf(ss), 1e-12f);
        va *= inv; vb *= inv;
        float pa = __shfl_xor(va, 1, 64), pb = __shfl_xor(vb, 1, 64);
        pk[i] = packb(va, pa); pk[4 + i] = packb(vb, pb);
      }
      if (!(lane & 1)) {
        int dw0 = c15 >> 1;
        #pragma unroll
        for (int i = 0; i < 4; ++i) {
          size_t base = (size_t)wbase[i] + h * 784;
          qws[base + dw0] = pk[i];
          qws[base + 8 + dw0] = pk[4 + i];
        }
      }
    }
    {   // k
      f32x4 a0 = acc[6 + 2 * h], a1 = acc[7 + 2 * h];
      unsigned pk[8];
      #pragma unroll
      for (int i = 0; i < 4; ++i) {
        float va = a0[i], vb = a1[i];
        float ss = va * va + vb * vb;
        ss += __shfl_xor(ss, 1, 64); ss += __shfl_xor(ss, 2, 64);
        ss += __shfl_xor(ss, 4, 64); ss += __shfl_xor(ss, 8, 64);
        float inv = 1.f / fmaxf(sqrtf(ss), 1e-12f);
        va *= inv; vb *= inv;
        float pa = __shfl_xor(va, 1, 64), pb = __shfl_xor(vb, 1, 64);
        pk[i] = packb(va, pa); pk[4 + i] = packb(vb, pb);
      }
      if (!(lane & 1)) {
        int dw0 = c15 >> 1;
        #pragma unroll
        for (int i = 0; i < 4; ++i) {
          size_t base = (size_t)wbase[i] + h * 784;
          kws[base + dw0] = pk[i];
          kws[base + 8 + dw0] = pk[4 + i];
        }
      }
    }
    {   // v
      f32x4 a0 = acc[12 + 2 * h], a1 = acc[13 + 2 * h];
      float b0 = v_bias[h * 32 + c15], b1 = v_bias[h * 32 + 16 + c15];
      unsigned pk[8];
      #pragma unroll
      for (int i = 0; i < 4; ++i) {
        float va = a0[i] + b0, vb = a1[i] + b1;
        float pa = __shfl_xor(va, 1, 64), pb = __shfl_xor(vb, 1, 64);
        pk[i] = packb(va, pa); pk[4 + i] = packb(vb, pb);
      }
      if (!(lane & 1)) {
        int dw0 = c15 >> 1;
        #pragma unroll
        for (int i = 0; i < 4; ++i) {
          size_t base = (size_t)wbase[i] + h * 784;
          vws[base + dw0] = pk[i];
          vws[base + 8 + dw0] = pk[4 + i];
        }
      }
    }
  }
}

// ---------------- K2: fully fused attention + proj + LN1 + MLP + LN2 ----------
// LDS carve (76288 B -> 2 blocks/CU), aliases guarded by barriers:
//   [0,13824)      VtS f16 V^T [3][32][72]         (dead after PV)
//   [13824,41472)  Ph  f16 P [3][64][72]           (dead after PV)
//   [0,25600)      ybuf f32 [64][100]: proj out -> x1 (in-place), lives to end
//   [25600,38912)  obuf [64][52] dw (O bf16)       (dead after proj reads)
//   [25600,75776)  hid [64][196] dw (fc1 out)      (dead after fc2 reads)
//   [25600,51200)  ybuf2 f32 [64][100] (fc2 out, aliases hid after fc2)
//   [75776,76288)  mu_s/rs_s (LN2)
__global__ __launch_bounds__(256) void attn_mlp_fused_kernel(
    const unsigned* __restrict__ qws, const unsigned* __restrict__ kws,
    const unsigned* __restrict__ vws, const float* __restrict__ bmtab,
    const unsigned* __restrict__ pwf, const float* __restrict__ proj_b,
    const float* __restrict__ x, const float* __restrict__ n1g,
    const float* __restrict__ n1b, const unsigned* __restrict__ w1f,
    const float* __restrict__ fc1_b, const unsigned* __restrict__ w2f,
    const float* __restrict__ fc2_b, const float* __restrict__ n2g,
    const float* __restrict__ n2b, float* __restrict__ out) {
  __shared__ __align__(16) unsigned smem[19072];   // 76288 B
  _Float16* VtS   = (_Float16*)smem;
  _Float16* Ph    = (_Float16*)((char*)smem + 13824);
  unsigned* Phd   = (unsigned*)((char*)smem + 13824);
  float*    ybuf  = (float*)smem;                      // x1 buffer [64][100]
  unsigned* obuf  = (unsigned*)((char*)smem + 25600);  // [64][52]
  unsigned* hid   = (unsigned*)((char*)smem + 25600);  // [64][196] dw
  float*    ybuf2 = (float*)((char*)smem + 25600);     // [64][100]
  float*    mu_s  = (float*)((char*)smem + 75776);     // [64]
  float*    rs_s  = (float*)((char*)smem + 76032);     // [64]

  int tid = threadIdx.x, lane = tid & 63, wv = tid >> 6;
  int c15 = lane & 15, q4 = lane >> 4;
  int win = blockIdx.x;
  int b = win >> 6, wi = win & 63, wh = wi >> 3, wcx = wi & 7;
  size_t wroot = (size_t)win * 2352;

  // ---- phase 1: stage V transposed as f16 ----
  for (int idx = tid; idx < 768; idx += 256) {
    int h2 = idx >> 8, rem = idx & 255;
    int t = rem >> 2, dg = rem & 3;
    int tc2 = t > 48 ? 48 : t;
    uint4 v4 = *(const uint4*)&vws[wroot + h2 * 784 + tc2 * 16 + dg * 4];
    _Float16* dst = &VtS[h2 * 2304 + (dg * 8) * 72 + t];
    dst[0 * 72] = (_Float16)blo(v4.x); dst[1 * 72] = (_Float16)bhi(v4.x);
    dst[2 * 72] = (_Float16)blo(v4.y); dst[3 * 72] = (_Float16)bhi(v4.y);
    dst[4 * 72] = (_Float16)blo(v4.z); dst[5 * 72] = (_Float16)bhi(v4.z);
    dst[6 * 72] = (_Float16)blo(v4.w); dst[7 * 72] = (_Float16)bhi(v4.w);
  }
  __syncthreads();

  // ---- phase 2: 3 (head,m-tile) tasks per wave ----
  f32x4 oall[3][2];
  #pragma unroll
  for (int t = 0; t < 3; ++t)
    #pragma unroll
    for (int n2 = 0; n2 < 2; ++n2) oall[t][n2] = f32x4{0.f, 0.f, 0.f, 0.f};

  #pragma unroll
  for (int t = 0; t < 3; ++t) {
    int id = wv * 3 + t;
    int h = id >> 2, mm = id & 3;
    size_t wb = wroot + (size_t)h * 784;

    int tq = mm * 16 + c15; if (tq > 48) tq = 48;
    bf16x8 qf = *(const bf16x8*)&qws[wb + tq * 16 + q4 * 4];
    bf16x8 kf[4];
    #pragma unroll
    for (int n = 0; n < 4; ++n) {
      int tk = n * 16 + c15; if (tk > 48) tk = 48;
      kf[n] = *(const bf16x8*)&kws[wb + tk * 16 + q4 * 4];
    }

    f32x4 s[4];
    #pragma unroll
    for (int n = 0; n < 4; ++n)
      s[n] = mfma16(qf, kf[n], f32x4{0.f, 0.f, 0.f, 0.f});

    const float* bm = bmtab + ((size_t)wi * 3 + h) * 2401;
    #pragma unroll
    for (int i = 0; i < 4; ++i) {
      int rw = mm * 16 + 4 * q4 + i;
      if (rw < 49) {
        const float* br = bm + rw * 49;
        #pragma unroll
        for (int n = 0; n < 4; ++n) {
          int j = n * 16 + c15;
          s[n][i] = (j < 49) ? (s[n][i] + br[j]) : -1e30f;
        }
      } else {
        #pragma unroll
        for (int n = 0; n < 4; ++n)
          if (n * 16 + c15 >= 49) s[n][i] = -1e30f;
      }
    }

    #pragma unroll
    for (int i = 0; i < 4; ++i) {
      float mx = fmaxf(fmaxf(s[0][i], s[1][i]), fmaxf(s[2][i], s[3][i]));
      mx = fmaxf(mx, __shfl_xor(mx, 1, 64)); mx = fmaxf(mx, __shfl_xor(mx, 2, 64));
      mx = fmaxf(mx, __shfl_xor(mx, 4, 64)); mx = fmaxf(mx, __shfl_xor(mx, 8, 64));
      float sum = 0.f;
      #pragma unroll
      for (int n = 0; n < 4; ++n) { float e = __expf(s[n][i] - mx); s[n][i] = e; sum += e; }
      sum += __shfl_xor(sum, 1, 64); sum += __shfl_xor(sum, 2, 64);
      sum += __shfl_xor(sum, 4, 64); sum += __shfl_xor(sum, 8, 64);
      float inv = 1.f / sum;
      #pragma unroll
      for (int n = 0; n < 4; ++n) s[n][i] *= inv;
    }

    #pragma unroll
    for (int n = 0; n < 4; ++n)
      #pragma unroll
      for (int i = 0; i < 4; ++i) {
        float pv = s[n][i];
        float pn = __shfl_xor(pv, 1, 64);
        if (!(lane & 1)) {
          int row = mm * 16 + 4 * q4 + i;
          Phd[h * 2304 + row * 36 + n * 8 + (c15 >> 1)] = packh(pv, pn);
        }
      }
    asm volatile("s_waitcnt lgkmcnt(0)" ::: "memory");
    __builtin_amdgcn_sched_barrier(0);

    #pragma unroll
    for (int ks = 0; ks < 2; ++ks) {
      f16x8 pa = *(const f16x8*)&Ph[h * 4608 + (mm * 16 + c15) * 72 + ks * 32 + q4 * 8];
      #pragma unroll
      for (int n2 = 0; n2 < 2; ++n2) {
        f16x8 vb = *(const f16x8*)&VtS[h * 2304 + (n2 * 16 + c15) * 72 + ks * 32 + q4 * 8];
        oall[t][n2] = mfma16h(pa, vb, oall[t][n2]);
      }
    }
  }
  __syncthreads();   // B1: VtS/Ph dead

  // ---- phase 3: O write (bf16 pairs) into obuf ----
  #pragma unroll
  for (int t = 0; t < 3; ++t) {
    int id = wv * 3 + t;
    int h = id >> 2, mm = id & 3;
    #pragma unroll
    for (int n2 = 0; n2 < 2; ++n2)
      #pragma unroll
      for (int i = 0; i < 4; ++i) {
        float ov = oall[t][n2][i];
        float on = __shfl_xor(ov, 1, 64);
        if (!(lane & 1))
          obuf[(mm * 16 + 4 * q4 + i) * 52 + h * 16 + n2 * 8 + (c15 >> 1)] = packb(ov, on);
      }
  }
  __syncthreads();   // B2

  // ---- phase 4: proj (wave wv -> M-tile wv), write y into ybuf ----
  bf16x8 oa[3];
  #pragma unroll
  for (int ks = 0; ks < 3; ++ks)
    oa[ks] = *(const bf16x8*)&obuf[(wv * 16 + c15) * 52 + ks * 16 + q4 * 4];
  f32x4 pr[6];
  #pragma unroll
  for (int n = 0; n < 6; ++n) pr[n] = f32x4{0.f, 0.f, 0.f, 0.f};
  #pragma unroll
  for (int n = 0; n < 6; ++n)
    #pragma unroll
    for (int ks = 0; ks < 3; ++ks) {
      bf16x8 bfr = *(const bf16x8*)&pwf[(size_t)((n * 3 + ks) * 64 + lane) * 4];
      pr[n] = mfma16(oa[ks], bfr, pr[n]);
    }
  #pragma unroll
  for (int n = 0; n < 6; ++n) {
    int col = n * 16 + c15;
    float bo = proj_b[col];
    #pragma unroll
    for (int i = 0; i < 4; ++i)
      ybuf[(wv * 16 + 4 * q4 + i) * 100 + col] = pr[n][i] + bo;
  }
  __syncthreads();   // B3

  // ---- phase 5: LN1 + residual, x1 written IN PLACE into ybuf ----
  {
    int t = tid >> 2, pp = tid & 3;
    if (t < 49) {
      float* yrow = ybuf + t * 100 + pp * 24;
      float s1 = 0.f;
      #pragma unroll
      for (int c = 0; c < 24; ++c) s1 += yrow[c];
      s1 += __shfl_xor(s1, 1, 64); s1 += __shfl_xor(s1, 2, 64);
      float mu = s1 * (1.f / 96.f);
      float v2 = 0.f;
      #pragma unroll
      for (int c = 0; c < 24; ++c) { float d = yrow[c] - mu; v2 += d * d; }
      v2 += __shfl_xor(v2, 1, 64); v2 += __shfl_xor(v2, 2, 64);
      float rs = rsqrtf(v2 * (1.f / 96.f) + 1e-5f);
      int tr = (t * 9363) >> 16, tc = t - tr * 7;
      int R = wh * 7 + tr + SHIFT_; if (R >= HW) R -= HW;
      int C = wcx * 7 + tc + SHIFT_; if (C >= HW) C -= HW;
      size_t base = ((size_t)(b * 3136 + R * 56 + C)) * 96 + pp * 24;
      #pragma unroll
      for (int c4 = 0; c4 < 6; ++c4) {
        float4 xv = *(const float4*)(x + base + c4 * 4);
        float4 gv = *(const float4*)(n1g + pp * 24 + c4 * 4);
        float4 bv = *(const float4*)(n1b + pp * 24 + c4 * 4);
        float4 ov;
        ov.x = xv.x + (yrow[c4 * 4 + 0] - mu) * rs * gv.x + bv.x;
        ov.y = xv.y + (yrow[c4 * 4 + 1] - mu) * rs * gv.y + bv.y;
        ov.z = xv.z + (yrow[c4 * 4 + 2] - mu) * rs * gv.z + bv.z;
        ov.w = xv.w + (yrow[c4 * 4 + 3] - mu) * rs * gv.w + bv.w;
        *(float4*)&yrow[c4 * 4] = ov;   // x1 in LDS (no global round trip)
      }
    }
  }
  __syncthreads();   // B4: ybuf now holds x1; obuf dead

  // ---- phase 6: fc1 + GELU -> hid ----
  bf16x8 afr[4][3];
  #pragma unroll
  for (int m = 0; m < 4; ++m)
    #pragma unroll
    for (int k = 0; k < 3; ++k) {
      const float* src = &ybuf[(m * 16 + c15) * 100 + k * 32 + q4 * 8];
      float4 a0 = *(const float4*)&src[0];
      float4 a1 = *(const float4*)&src[4];
      afr[m][k] = mk8(packb(a0.x, a0.y), packb(a0.z, a0.w),
                      packb(a1.x, a1.y), packb(a1.z, a1.w));
    }
  f32x4 acc[4][6];
  #pragma unroll
  for (int m = 0; m < 4; ++m)
    #pragma unroll
    for (int n = 0; n < 6; ++n) acc[m][n] = f32x4{0.f, 0.f, 0.f, 0.f};
  #pragma unroll
  for (int n = 0; n < 6; ++n) {
    #pragma unroll
    for (int k = 0; k < 3; ++k) {
      bf16x8 bb = *(const bf16x8*)&w1f[(size_t)(((6 * wv + n) * 3 + k) * 64 + lane) * 4];
      #pragma unroll
      for (int m = 0; m < 4; ++m) acc[m][n] = mfma16(afr[m][k], bb, acc[m][n]);
    }
  }
  {
    unsigned short* hidb = (unsigned short*)hid;
    #pragma unroll
    for (int n = 0; n < 6; ++n) {
      int col = (6 * wv + n) * 16 + c15;
      float bo = fc1_b[col];
      #pragma unroll
      for (int m = 0; m < 4; ++m) {
        #pragma unroll
        for (int i = 0; i < 4; ++i) {
          float g = gelu_f(acc[m][n][i] + bo);
          hidb[(m * 16 + q4 * 4 + i) * 392 + col] = f2b(g);
        }
      }
    }
  }
  __syncthreads();   // B5

  // ---- phase 7: fc2 ----
  f32x4 acc2[6];
  #pragma unroll
  for (int n = 0; n < 6; ++n) acc2[n] = f32x4{0.f, 0.f, 0.f, 0.f};
  #pragma unroll
  for (int k = 0; k < 12; ++k) {
    bf16x8 a = *(const bf16x8*)&hid[(wv * 16 + c15) * 196 + k * 16 + q4 * 4];
    #pragma unroll
    for (int n = 0; n < 6; ++n) {
      bf16x8 bb = *(const bf16x8*)&w2f[(size_t)((n * 12 + k) * 64 + lane) * 4];
      acc2[n] = mfma16(a, bb, acc2[n]);
    }
  }
  __syncthreads();   // B6: hid reads done -> ybuf2 alias safe

  #pragma unroll
  for (int n = 0; n < 6; ++n) {
    int col = n * 16 + c15;
    float bo = fc2_b[col];
    #pragma unroll
    for (int i = 0; i < 4; ++i)
      ybuf2[(wv * 16 + q4 * 4 + i) * 100 + col] = acc2[n][i] + bo;
  }
  __syncthreads();   // B7

  // ---- phase 8: LN2 stats ----
  {
    int t = tid >> 2, p = tid & 3;
    const float* row = ybuf2 + t * 100 + p * 24;
    float s = 0.f, s2 = 0.f;
    for (int c = 0; c < 24; ++c) { float v = row[c]; s += v; s2 += v * v; }
    s += __shfl_xor(s, 1, 64); s2 += __shfl_xor(s2, 1, 64);
    s += __shfl_xor(s, 2, 64); s2 += __shfl_xor(s2, 2, 64);
    if (p == 0) {
      float mu = s * (1.f / 96.f);
      float var = s2 * (1.f / 96.f) - mu * mu;
      mu_s[t] = mu;
      rs_s[t] = rsqrtf(fmaxf(var, 0.f) + 1e-5f);
    }
  }
  __syncthreads();   // B8

  // ---- phase 9: final = x1 + LN2(h), scatter to original layout ----
  {
    int t = tid >> 2, pp = tid & 3;
    if (t < 49) {
      float mu = mu_s[t], rs = rs_s[t];
      int tr = (t * 9363) >> 16, tc = t - tr * 7;
      int R = wh * 7 + tr + SHIFT_; if (R >= HW) R -= HW;
      int C = wcx * 7 + tc + SHIFT_; if (C >= HW) C -= HW;
      size_t base = ((size_t)(b * 3136 + R * 56 + C)) * 96 + pp * 24;
      #pragma unroll
      for (int c4 = 0; c4 < 6; ++c4) {
        float4 x1v = *(float4*)&ybuf[t * 100 + pp * 24 + c4 * 4];
        float4 h4  = *(float4*)&ybuf2[t * 100 + pp * 24 + c4 * 4];
        float4 g4  = *(const float4*)&n2g[pp * 24 + c4 * 4];
        float4 b4  = *(const float4*)&n2b[pp * 24 + c4 * 4];
        float4 ov;
        ov.x = x1v.x + (h4.x - mu) * rs * g4.x + b4.x;
        ov.y = x1v.y + (h4.y - mu) * rs * g4.y + b4.y;
        ov.z = x1v.z + (h4.z - mu) * rs * g4.z + b4.z;
        ov.w = x1v.w + (h4.w - mu) * rs * g4.w + b4.w;
        *(float4*)(out + base + c4 * 4) = ov;
      }
    }
  }
}

// ---------------- launch ------------------------------------------------------
extern "C" void kernel_launch(void* const* d_in, const int* in_sizes, int n_in,
                              void* d_out, int out_size, void* d_ws, size_t ws_size,
                              hipStream_t stream) {
  const float* x           = (const float*)d_in[0];
  const float* attn_mask   = (const float*)d_in[1];
  const float* qkv_w       = (const float*)d_in[2];
  const float* q_bias      = (const float*)d_in[3];
  const float* v_bias      = (const float*)d_in[4];
  const float* logit_scale = (const float*)d_in[5];
  const float* cpb_w1      = (const float*)d_in[6];
  const float* cpb_b1      = (const float*)d_in[7];
  const float* cpb_w2      = (const float*)d_in[8];
  const float* proj_w      = (const float*)d_in[9];
  const float* proj_b      = (const float*)d_in[10];
  const float* n1g         = (const float*)d_in[11];
  const float* n1b         = (const float*)d_in[12];
  const float* fc1_w       = (const float*)d_in[13];
  const float* fc1_b       = (const float*)d_in[14];
  const float* fc2_w       = (const float*)d_in[15];
  const float* fc2_b       = (const float*)d_in[16];
  const float* n2g         = (const float*)d_in[17];
  const float* n2b         = (const float*)d_in[18];
  float* out = (float*)d_out;

  // ---- workspace layout ----
  float* tab     = (float*)d_ws;                       // 512 f32
  float* bmtab   = tab + 512;                          // 460992 f32 (1.84 MB)
  unsigned* qkvf = (unsigned*)(bmtab + 460992);        // 13824 dw
  unsigned* w1f  = qkvf + 13824;                       // 18432 dw
  unsigned* w2f  = w1f + 18432;                        // 18432 dw
  unsigned* pwf  = w2f + 18432;                        // 4608 dw
  unsigned* qws  = pwf + 4608;                         // 9,633,792 dw each
  unsigned* kws  = qws + 9633792;
  unsigned* vws  = kws + 9633792;

  wconv2_kernel<<<54, 256, 0, stream>>>(qkv_w, fc1_w, fc2_w, proj_w,
                                        qkvf, w1f, w2f, pwf);
  cpb_table_kernel<<<1, 512, 0, stream>>>(cpb_w1, cpb_b1, cpb_w2, tab);
  bm_kernel<<<(64 * NHEADS * NTOK * NTOK + 255) / 256, 256, 0, stream>>>(
      tab, attn_mask, bmtab);
  qkv_mfma_kernel<<<NTOKENS / 64, 256, 0, stream>>>(x, qkvf, q_bias, v_bias,
                                                    logit_scale, qws, kws, vws);
  attn_mlp_fused_kernel<<<NWIN_TOT, 256, 0, stream>>>(
      qws, kws, vws, bmtab, pwf, proj_b, x, n1g, n1b,
      w1f, fc1_b, w2f, fc2_b, n2g, n2b, out);
}

// Round 15
// 436.273 us; speedup vs baseline: 1.0406x; 1.0406x over previous
//
#include <hip/hip_runtime.h>
#include <math.h>

#define BATCH 64
#define HW 56
#define CDIM 96
#define NHEADS 3
#define WSZ 7
#define NTOK 49
#define SHIFT_ 3
#define NWIN_TOT 4096
#define HID 384
#define NTOKENS (BATCH * HW * HW)   // 200704
#define LN100 4.6051702f

typedef __attribute__((ext_vector_type(8))) short bf16x8;
typedef __attribute__((ext_vector_type(8))) _Float16 f16x8;
typedef __attribute__((ext_vector_type(4))) float f32x4;

__device__ inline f32x4 mfma16(bf16x8 a, bf16x8 b, f32x4 c) {
  return __builtin_amdgcn_mfma_f32_16x16x32_bf16(a, b, c, 0, 0, 0);
}
__device__ inline f32x4 mfma16h(f16x8 a, f16x8 b, f32x4 c) {
  return __builtin_amdgcn_mfma_f32_16x16x32_f16(a, b, c, 0, 0, 0);
}

// ---------- bf16/f16 helpers ----------
__device__ inline unsigned short f2b(float f) {
  unsigned u = __float_as_uint(f);
  unsigned r = (u + 0x7FFFu + ((u >> 16) & 1u)) >> 16;
  return (unsigned short)r;
}
__device__ inline float blo(unsigned u) { return __uint_as_float(u << 16); }
__device__ inline float bhi(unsigned u) { return __uint_as_float(u & 0xFFFF0000u); }
__device__ inline unsigned packb(float a, float b) {
  return (unsigned)f2b(a) | ((unsigned)f2b(b) << 16);
}
__device__ inline unsigned packh(float a, float b) {
  _Float16 ha = (_Float16)a, hb = (_Float16)b;
  unsigned short ua = *(unsigned short*)&ha, ub = *(unsigned short*)&hb;
  return (unsigned)ua | ((unsigned)ub << 16);
}
// GELU with A&S 7.1.26 erf (max abs err 1.5e-7)
__device__ inline float gelu_f(float v) {
  float a = fabsf(v) * 0.70710678118654752f;
  float t = 1.0f / fmaf(a, 0.3275911f, 1.0f);
  float p = t * fmaf(t, fmaf(t, fmaf(t, fmaf(t, 1.061405429f, -1.453152027f),
                                     1.421413741f), -0.284496736f), 0.254829592f);
  float er = 1.0f - p * __expf(-a * a);
  er = (v < 0.f) ? -er : er;
  return 0.5f * v * (1.0f + er);
}

// ---------------- P0: weight conversion into MFMA B-frag layouts --------------
__global__ __launch_bounds__(256) void wconv2_kernel(
    const float* __restrict__ qkv_w, const float* __restrict__ fc1_w,
    const float* __restrict__ fc2_w, const float* __restrict__ proj_w,
    unsigned* __restrict__ qkvf, unsigned* __restrict__ w1f,
    unsigned* __restrict__ w2f, unsigned* __restrict__ pwf) {
  int T = blockIdx.x * 256 + threadIdx.x;
  if (T < 3456) {  // qkv: 18 n-tiles x 3 k-steps
    int tk = T >> 6, l = T & 63;
    int n = tk / 3, ks = tk - n * 3;
    int o = n * 16 + (l & 15);
    const float* src = qkv_w + o * 96 + ks * 32 + (l >> 4) * 8;
    uint4 d;
    d.x = packb(src[0], src[1]); d.y = packb(src[2], src[3]);
    d.z = packb(src[4], src[5]); d.w = packb(src[6], src[7]);
    *(uint4*)&qkvf[(size_t)(tk * 64 + l) * 4] = d;
    return;
  }
  T -= 3456;
  if (T < 4608) {  // fc1
    int tk = T >> 6, l = T & 63;
    int n = tk / 3, ks = tk - n * 3;
    int o = n * 16 + (l & 15);
    const float* src = fc1_w + o * 96 + ks * 32 + (l >> 4) * 8;
    uint4 d;
    d.x = packb(src[0], src[1]); d.y = packb(src[2], src[3]);
    d.z = packb(src[4], src[5]); d.w = packb(src[6], src[7]);
    *(uint4*)&w1f[(size_t)(tk * 64 + l) * 4] = d;
    return;
  }
  T -= 4608;
  if (T < 4608) {  // fc2
    int tk = T >> 6, l = T & 63;
    int n = tk / 12, ks = tk - n * 12;
    int o = n * 16 + (l & 15);
    const float* src = fc2_w + o * 384 + ks * 32 + (l >> 4) * 8;
    uint4 d;
    d.x = packb(src[0], src[1]); d.y = packb(src[2], src[3]);
    d.z = packb(src[4], src[5]); d.w = packb(src[6], src[7]);
    *(uint4*)&w2f[(size_t)(tk * 64 + l) * 4] = d;
    return;
  }
  T -= 4608;
  if (T < 1152) {  // proj
    int tk = T >> 6, l = T & 63;
    int n = tk / 3, ks = tk - n * 3;
    int o = n * 16 + (l & 15);
    const float* src = proj_w + o * 96 + ks * 32 + (l >> 4) * 8;
    uint4 d;
    d.x = packb(src[0], src[1]); d.y = packb(src[2], src[3]);
    d.z = packb(src[4], src[5]); d.w = packb(src[6], src[7]);
    *(uint4*)&pwf[(size_t)(tk * 64 + l) * 4] = d;
  }
}

// ---------------- P1: CPB MLP table raw (169 x 3) -----------------------------
__global__ __launch_bounds__(512) void cpb_table_kernel(
    const float* __restrict__ w1, const float* __restrict__ b1,
    const float* __restrict__ w2, float* __restrict__ tabout) {
  int tid = threadIdx.x;
  if (tid >= 169 * 3) return;
  int e = tid / 3, h = tid - e * 3;
  int i = e / 13, j = e - i * 13;
  float ti = (float)(i - 6) * (8.0f / 6.0f);
  float tj = (float)(j - 6) * (8.0f / 6.0f);
  float sx = (ti > 0.f) ? 1.f : (ti < 0.f ? -1.f : 0.f);
  float sy = (tj > 0.f) ? 1.f : (tj < 0.f ? -1.f : 0.f);
  float tx = sx * log2f(fabsf(ti) + 1.f) * (1.0f / 3.0f);
  float ty = sy * log2f(fabsf(tj) + 1.f) * (1.0f / 3.0f);
  float acc = 0.f;
  for (int jj = 0; jj < 512; ++jj) {
    float hv = tx * w1[jj * 2 + 0] + ty * w1[jj * 2 + 1] + b1[jj];
    float g = 0.5f * hv * (1.f + erff(hv * 0.70710678118654752f));
    acc += g * w2[h * 512 + jj];
  }
  tabout[e * 3 + h] = acc;
}

// ---------------- P2: combined 16*sigmoid(rpb) + shift-mask table -------------
__global__ __launch_bounds__(256) void bm_kernel(
    const float* __restrict__ tabout, const float* __restrict__ mask,
    float* __restrict__ bmtab) {
  int idx = blockIdx.x * 256 + threadIdx.x;
  if (idx >= 64 * NHEADS * NTOK * NTOK) return;
  int wi = idx / (NHEADS * 2401);
  int rem = idx - wi * (NHEADS * 2401);
  int h = rem / 2401, ij = rem - h * 2401;
  int i = ij / NTOK, j = ij - i * NTOK;
  int ri = (i / WSZ) - (j / WSZ) + 6;
  int ci = (i % WSZ) - (j % WSZ) + 6;
  int e = ri * 13 + ci;
  float v = tabout[e * 3 + h];
  bmtab[idx] = 16.f / (1.f + expf(-v)) + mask[(size_t)wi * 2401 + ij];
}

// ---------------- K1: token-major QKV GEMM (MFMA) + cosine norm ---------------
// Output layout: WINDOW-MAJOR [win][h][t][16 dw] so attn reads are coalesced.
__global__ __launch_bounds__(256) void qkv_mfma_kernel(
    const float* __restrict__ x, const unsigned* __restrict__ qkvf,
    const float* __restrict__ q_bias, const float* __restrict__ v_bias,
    const float* __restrict__ logit_scale,
    unsigned* __restrict__ qws, unsigned* __restrict__ kws,
    unsigned* __restrict__ vws) {
  __shared__ unsigned xa[64 * 52];
  int tid = threadIdx.x, lane = tid & 63, wv = tid >> 6;
  size_t tok0 = (size_t)blockIdx.x * 64;

  for (int idx = tid; idx < 3072; idx += 256) {
    int t = idx / 48, c2 = idx - t * 48;
    const float2 s = *(const float2*)(x + (tok0 + t) * 96 + c2 * 2);
    xa[t * 52 + c2] = packb(s.x, s.y);
  }
  __syncthreads();

  int c15 = lane & 15, q4 = lane >> 4;
  bf16x8 afr[3];
  #pragma unroll
  for (int k = 0; k < 3; ++k)
    afr[k] = *(const bf16x8*)&xa[(wv * 16 + c15) * 52 + k * 16 + q4 * 4];

  f32x4 acc[18];
  #pragma unroll
  for (int n = 0; n < 18; ++n) acc[n] = f32x4{0.f, 0.f, 0.f, 0.f};
  #pragma unroll
  for (int n = 0; n < 18; ++n) {
    #pragma unroll
    for (int k = 0; k < 3; ++k) {
      bf16x8 b = *(const bf16x8*)&qkvf[(size_t)((n * 3 + k) * 64 + lane) * 4];
      acc[n] = mfma16(afr[k], b, acc[n]);
    }
  }

  // window-major destination base for each of my 4 tokens
  int tokr0 = (int)tok0 + wv * 16 + q4 * 4;
  int wbase[4];
  #pragma unroll
  for (int i = 0; i < 4; ++i) {
    int tk = tokr0 + i;
    int bb = tk / 3136, rem = tk - bb * 3136;
    int R = rem / 56, C = rem - R * 56;
    int rr = R + 53; if (rr >= 56) rr -= 56;    // rolled row
    int cc = C + 53; if (cc >= 56) cc -= 56;    // rolled col
    int wr = rr / 7, tr2 = rr - wr * 7;
    int wc = cc / 7, tc2 = cc - wc * 7;
    wbase[i] = (bb * 64 + wr * 8 + wc) * 2352 + (tr2 * 7 + tc2) * 16;
  }

  #pragma unroll
  for (int h = 0; h < 3; ++h) {
    float sc = expf(fminf(logit_scale[h], LN100));
    {   // q
      f32x4 a0 = acc[2 * h], a1 = acc[2 * h + 1];
      float b0 = q_bias[h * 32 + c15], b1 = q_bias[h * 32 + 16 + c15];
      unsigned pk[8];
      #pragma unroll
      for (int i = 0; i < 4; ++i) {
        float va = a0[i] + b0, vb = a1[i] + b1;
        float ss = va * va + vb * vb;
        ss += __shfl_xor(ss, 1, 64); ss += __shfl_xor(ss, 2, 64);
        ss += __shfl_xor(ss, 4, 64); ss += __shfl_xor(ss, 8, 64);
        float inv = sc / fmaxf(sqrtf(ss), 1e-12f);
        va *= inv; vb *= inv;
        float pa = __shfl_xor(va, 1, 64), pb = __shfl_xor(vb, 1, 64);
        pk[i] = packb(va, pa); pk[4 + i] = packb(vb, pb);
      }
      if (!(lane & 1)) {
        int dw0 = c15 >> 1;
        #pragma unroll
        for (int i = 0; i < 4; ++i) {
          size_t base = (size_t)wbase[i] + h * 784;
          qws[base + dw0] = pk[i];
          qws[base + 8 + dw0] = pk[4 + i];
        }
      }
    }
    {   // k
      f32x4 a0 = acc[6 + 2 * h], a1 = acc[7 + 2 * h];
      unsigned pk[8];
      #pragma unroll
      for (int i = 0; i < 4; ++i) {
        float va = a0[i], vb = a1[i];
        float ss = va * va + vb * vb;
        ss += __shfl_xor(ss, 1, 64); ss += __shfl_xor(ss, 2, 64);
        ss += __shfl_xor(ss, 4, 64); ss += __shfl_xor(ss, 8, 64);
        float inv = 1.f / fmaxf(sqrtf(ss), 1e-12f);
        va *= inv; vb *= inv;
        float pa = __shfl_xor(va, 1, 64), pb = __shfl_xor(vb, 1, 64);
        pk[i] = packb(va, pa); pk[4 + i] = packb(vb, pb);
      }
      if (!(lane & 1)) {
        int dw0 = c15 >> 1;
        #pragma unroll
        for (int i = 0; i < 4; ++i) {
          size_t base = (size_t)wbase[i] + h * 784;
          kws[base + dw0] = pk[i];
          kws[base + 8 + dw0] = pk[4 + i];
        }
      }
    }
    {   // v
      f32x4 a0 = acc[12 + 2 * h], a1 = acc[13 + 2 * h];
      float b0 = v_bias[h * 32 + c15], b1 = v_bias[h * 32 + 16 + c15];
      unsigned pk[8];
      #pragma unroll
      for (int i = 0; i < 4; ++i) {
        float va = a0[i] + b0, vb = a1[i] + b1;
        float pa = __shfl_xor(va, 1, 64), pb = __shfl_xor(vb, 1, 64);
        pk[i] = packb(va, pa); pk[4 + i] = packb(vb, pb);
      }
      if (!(lane & 1)) {
        int dw0 = c15 >> 1;
        #pragma unroll
        for (int i = 0; i < 4; ++i) {
          size_t base = (size_t)wbase[i] + h * 784;
          vws[base + dw0] = pk[i];
          vws[base + 8 + dw0] = pk[4 + i];
        }
      }
    }
  }
}

// ---------------- K2: fused attention + proj + LN1 ----------------------------
// 12 (head, m-tile) tasks distributed 3-per-wave -> all 4 waves busy in the
// attention phase. Each task is self-contained (PV reads only its own P rows).
// LDS carve (41472 B), aliases guarded by barriers:
//   region A [0,13824):      VtS f16 V^T [3][32][72]  -> obuf [64][52] dw after PV
//   region B [13824,41472):  Ph  f16 P  [3][64][72]   -> ybuf f32 [64][100] after PV
__global__ __launch_bounds__(256) void attn_fused_kernel(
    const unsigned* __restrict__ qws, const unsigned* __restrict__ kws,
    const unsigned* __restrict__ vws, const float* __restrict__ bmtab,
    const unsigned* __restrict__ pwf, const float* __restrict__ proj_b,
    const float* __restrict__ x, const float* __restrict__ n1g,
    const float* __restrict__ n1b, float* __restrict__ out) {
  __shared__ __align__(16) unsigned smem[10368];   // 41472 B
  _Float16* VtS  = (_Float16*)smem;                        // [3][32][72]
  unsigned* obuf = (unsigned*)smem;                        // [64][52] (alias, post-PV)
  _Float16* Ph   = (_Float16*)((char*)smem + 13824);       // [3][64][72]
  unsigned* Phd  = (unsigned*)((char*)smem + 13824);       // dword view, row stride 36
  float*    ybuf = (float*)((char*)smem + 13824);          // [64][100] (alias, post-PV)

  int tid = threadIdx.x, lane = tid & 63, wv = tid >> 6;
  int c15 = lane & 15, q4 = lane >> 4;
  int win = blockIdx.x;
  int b = win >> 6, wi = win & 63, wh = wi >> 3, wcx = wi & 7;
  size_t wroot = (size_t)win * 2352;

  // stage V transposed as f16 (coalesced reads); cols 49..63 clamped junk (P=0)
  for (int idx = tid; idx < 768; idx += 256) {
    int h2 = idx >> 8, rem = idx & 255;
    int t = rem >> 2, dg = rem & 3;
    int tc2 = t > 48 ? 48 : t;
    uint4 v4 = *(const uint4*)&vws[wroot + h2 * 784 + tc2 * 16 + dg * 4];
    _Float16* dst = &VtS[h2 * 2304 + (dg * 8) * 72 + t];
    dst[0 * 72] = (_Float16)blo(v4.x); dst[1 * 72] = (_Float16)bhi(v4.x);
    dst[2 * 72] = (_Float16)blo(v4.y); dst[3 * 72] = (_Float16)bhi(v4.y);
    dst[4 * 72] = (_Float16)blo(v4.z); dst[5 * 72] = (_Float16)bhi(v4.z);
    dst[6 * 72] = (_Float16)blo(v4.w); dst[7 * 72] = (_Float16)bhi(v4.w);
  }
  __syncthreads();

  // ---- 3 tasks per wave: id = wv*3+t -> h = id>>2, mm = id&3 ----
  f32x4 oall[3][2];
  #pragma unroll
  for (int t = 0; t < 3; ++t)
    #pragma unroll
    for (int n2 = 0; n2 < 2; ++n2) oall[t][n2] = f32x4{0.f, 0.f, 0.f, 0.f};

  #pragma unroll
  for (int t = 0; t < 3; ++t) {
    int id = wv * 3 + t;
    int h = id >> 2, mm = id & 3;
    size_t wb = wroot + (size_t)h * 784;

    int tq = mm * 16 + c15; if (tq > 48) tq = 48;
    bf16x8 qf = *(const bf16x8*)&qws[wb + tq * 16 + q4 * 4];
    bf16x8 kf[4];
    #pragma unroll
    for (int n = 0; n < 4; ++n) {
      int tk = n * 16 + c15; if (tk > 48) tk = 48;
      kf[n] = *(const bf16x8*)&kws[wb + tk * 16 + q4 * 4];
    }

    f32x4 s[4];
    #pragma unroll
    for (int n = 0; n < 4; ++n)
      s[n] = mfma16(qf, kf[n], f32x4{0.f, 0.f, 0.f, 0.f});

    // combined bias+mask table
    const float* bm = bmtab + ((size_t)wi * 3 + h) * 2401;
    #pragma unroll
    for (int i = 0; i < 4; ++i) {
      int rw = mm * 16 + 4 * q4 + i;
      if (rw < 49) {
        const float* br = bm + rw * 49;
        #pragma unroll
        for (int n = 0; n < 4; ++n) {
          int j = n * 16 + c15;
          s[n][i] = (j < 49) ? (s[n][i] + br[j]) : -1e30f;
        }
      } else {
        #pragma unroll
        for (int n = 0; n < 4; ++n)
          if (n * 16 + c15 >= 49) s[n][i] = -1e30f;
      }
    }

    // in-register softmax (row = 16 lanes x 4 n-tiles)
    #pragma unroll
    for (int i = 0; i < 4; ++i) {
      float mx = fmaxf(fmaxf(s[0][i], s[1][i]), fmaxf(s[2][i], s[3][i]));
      mx = fmaxf(mx, __shfl_xor(mx, 1, 64)); mx = fmaxf(mx, __shfl_xor(mx, 2, 64));
      mx = fmaxf(mx, __shfl_xor(mx, 4, 64)); mx = fmaxf(mx, __shfl_xor(mx, 8, 64));
      float sum = 0.f;
      #pragma unroll
      for (int n = 0; n < 4; ++n) { float e = __expf(s[n][i] - mx); s[n][i] = e; sum += e; }
      sum += __shfl_xor(sum, 1, 64); sum += __shfl_xor(sum, 2, 64);
      sum += __shfl_xor(sum, 4, 64); sum += __shfl_xor(sum, 8, 64);
      float inv = 1.f / sum;
      #pragma unroll
      for (int n = 0; n < 4; ++n) s[n][i] *= inv;
    }

    // write P as f16 packed pairs (even lanes, ds_write_b32, row stride 36 dw)
    #pragma unroll
    for (int n = 0; n < 4; ++n)
      #pragma unroll
      for (int i = 0; i < 4; ++i) {
        float pv = s[n][i];
        float pn = __shfl_xor(pv, 1, 64);
        if (!(lane & 1)) {
          int row = mm * 16 + 4 * q4 + i;
          Phd[h * 2304 + row * 36 + n * 8 + (c15 >> 1)] = packh(pv, pn);
        }
      }
    // fence: cross-lane same-wave LDS RAW
    asm volatile("s_waitcnt lgkmcnt(0)" ::: "memory");
    __builtin_amdgcn_sched_barrier(0);

    // PV in f16 (8 MFMAs/task)
    #pragma unroll
    for (int ks = 0; ks < 2; ++ks) {
      f16x8 pa = *(const f16x8*)&Ph[h * 4608 + (mm * 16 + c15) * 72 + ks * 32 + q4 * 8];
      #pragma unroll
      for (int n2 = 0; n2 < 2; ++n2) {
        f16x8 vb = *(const f16x8*)&VtS[h * 2304 + (n2 * 16 + c15) * 72 + ks * 32 + q4 * 8];
        oall[t][n2] = mfma16h(pa, vb, oall[t][n2]);
      }
    }
  }
  __syncthreads();   // all PV reads done -> VtS/Ph dead -> obuf/ybuf aliases safe

  // write O (bf16 pairs) into obuf (aliases VtS region)
  #pragma unroll
  for (int t = 0; t < 3; ++t) {
    int id = wv * 3 + t;
    int h = id >> 2, mm = id & 3;
    #pragma unroll
    for (int n2 = 0; n2 < 2; ++n2)
      #pragma unroll
      for (int i = 0; i < 4; ++i) {
        float ov = oall[t][n2][i];
        float on = __shfl_xor(ov, 1, 64);
        if (!(lane & 1))
          obuf[(mm * 16 + 4 * q4 + i) * 52 + h * 16 + n2 * 8 + (c15 >> 1)] = packb(ov, on);
      }
  }
  __syncthreads();

  // ---- proj: wave wv handles M-tile wv ----
  bf16x8 oa[3];
  #pragma unroll
  for (int ks = 0; ks < 3; ++ks)
    oa[ks] = *(const bf16x8*)&obuf[(wv * 16 + c15) * 52 + ks * 16 + q4 * 4];
  f32x4 pr[6];
  #pragma unroll
  for (int n = 0; n < 6; ++n) pr[n] = f32x4{0.f, 0.f, 0.f, 0.f};
  #pragma unroll
  for (int n = 0; n < 6; ++n)
    #pragma unroll
    for (int ks = 0; ks < 3; ++ks) {
      bf16x8 bfr = *(const bf16x8*)&pwf[(size_t)((n * 3 + ks) * 64 + lane) * 4];
      pr[n] = mfma16(oa[ks], bfr, pr[n]);
    }

  #pragma unroll
  for (int n = 0; n < 6; ++n) {
    int col = n * 16 + c15;
    float bo = proj_b[col];
    #pragma unroll
    for (int i = 0; i < 4; ++i)
      ybuf[(wv * 16 + 4 * q4 + i) * 100 + col] = pr[n][i] + bo;
  }
  __syncthreads();

  // ---- LN1 (two-pass variance) + residual scatter (arithmetic address) ----
  int t = tid >> 2, pp = tid & 3;
  if (t < 49) {
    const float* yrow = ybuf + t * 100 + pp * 24;
    float s1 = 0.f;
    #pragma unroll
    for (int c = 0; c < 24; ++c) s1 += yrow[c];
    s1 += __shfl_xor(s1, 1, 64); s1 += __shfl_xor(s1, 2, 64);
    float mu = s1 * (1.f / 96.f);
    float v2 = 0.f;
    #pragma unroll
    for (int c = 0; c < 24; ++c) { float d = yrow[c] - mu; v2 += d * d; }
    v2 += __shfl_xor(v2, 1, 64); v2 += __shfl_xor(v2, 2, 64);
    float rs = rsqrtf(v2 * (1.f / 96.f) + 1e-5f);
    int tr = (t * 9363) >> 16, tc = t - tr * 7;
    int R = wh * 7 + tr + SHIFT_; if (R >= HW) R -= HW;
    int C = wcx * 7 + tc + SHIFT_; if (C >= HW) C -= HW;
    size_t base = ((size_t)(b * 3136 + R * 56 + C)) * 96 + pp * 24;
    #pragma unroll
    for (int c4 = 0; c4 < 6; ++c4) {
      float4 xv = *(const float4*)(x + base + c4 * 4);
      float4 gv = *(const float4*)(n1g + pp * 24 + c4 * 4);
      float4 bv = *(const float4*)(n1b + pp * 24 + c4 * 4);
      float4 ov;
      ov.x = xv.x + (yrow[c4 * 4 + 0] - mu) * rs * gv.x + bv.x;
      ov.y = xv.y + (yrow[c4 * 4 + 1] - mu) * rs * gv.y + bv.y;
      ov.z = xv.z + (yrow[c4 * 4 + 2] - mu) * rs * gv.z + bv.z;
      ov.w = xv.w + (yrow[c4 * 4 + 3] - mu) * rs * gv.w + bv.w;
      *(float4*)(out + base + c4 * 4) = ov;
    }
  }
}

// ---------------- K4: MLP via MFMA + LN2 + residual (in-place) ----------------
__global__ __launch_bounds__(256) void mlp_mfma_kernel(
    const unsigned* __restrict__ w1f, const float* __restrict__ fc1_b,
    const unsigned* __restrict__ w2f, const float* __restrict__ fc2_b,
    const float* __restrict__ n2g, const float* __restrict__ n2b,
    float* __restrict__ xio) {
  __shared__ unsigned xa[64 * 52];
  __shared__ unsigned hid[64 * 196];
  __shared__ float mu_s[64], rs_s[64];
  int tid = threadIdx.x, lane = tid & 63, wv = tid >> 6;
  int c15 = lane & 15, q4 = lane >> 4;
  size_t tok0 = (size_t)blockIdx.x * 64;

  for (int idx = tid; idx < 3072; idx += 256) {
    int t = idx / 48, c2 = idx - t * 48;
    const float2 s = *(const float2*)(xio + (tok0 + t) * 96 + c2 * 2);
    xa[t * 52 + c2] = packb(s.x, s.y);
  }
  __syncthreads();

  bf16x8 afr[4][3];
  #pragma unroll
  for (int m = 0; m < 4; ++m)
    #pragma unroll
    for (int k = 0; k < 3; ++k)
      afr[m][k] = *(const bf16x8*)&xa[(m * 16 + c15) * 52 + k * 16 + q4 * 4];
  f32x4 acc[4][6];
  #pragma unroll
  for (int m = 0; m < 4; ++m)
    #pragma unroll
    for (int n = 0; n < 6; ++n) acc[m][n] = f32x4{0.f, 0.f, 0.f, 0.f};
  #pragma unroll
  for (int n = 0; n < 6; ++n) {
    #pragma unroll
    for (int k = 0; k < 3; ++k) {
      bf16x8 b = *(const bf16x8*)&w1f[(size_t)(((6 * wv + n) * 3 + k) * 64 + lane) * 4];
      #pragma unroll
      for (int m = 0; m < 4; ++m) acc[m][n] = mfma16(afr[m][k], b, acc[m][n]);
    }
  }
  unsigned short* hidb = (unsigned short*)hid;
  #pragma unroll
  for (int n = 0; n < 6; ++n) {
    int col = (6 * wv + n) * 16 + c15;
    float bo = fc1_b[col];
    #pragma unroll
    for (int m = 0; m < 4; ++m) {
      #pragma unroll
      for (int i = 0; i < 4; ++i) {
        float g = gelu_f(acc[m][n][i] + bo);
        hidb[(m * 16 + q4 * 4 + i) * 392 + col] = f2b(g);
      }
    }
  }
  __syncthreads();

  f32x4 acc2[6];
  #pragma unroll
  for (int n = 0; n < 6; ++n) acc2[n] = f32x4{0.f, 0.f, 0.f, 0.f};
  #pragma unroll
  for (int k = 0; k < 12; ++k) {
    bf16x8 a = *(const bf16x8*)&hid[(wv * 16 + c15) * 196 + k * 16 + q4 * 4];
    #pragma unroll
    for (int n = 0; n < 6; ++n) {
      bf16x8 b = *(const bf16x8*)&w2f[(size_t)((n * 12 + k) * 64 + lane) * 4];
      acc2[n] = mfma16(a, b, acc2[n]);
    }
  }
  __syncthreads();

  float* ybuf = (float*)hid;
  #pragma unroll
  for (int n = 0; n < 6; ++n) {
    int col = n * 16 + c15;
    float bo = fc2_b[col];
    #pragma unroll
    for (int i = 0; i < 4; ++i)
      ybuf[(wv * 16 + q4 * 4 + i) * 100 + col] = acc2[n][i] + bo;
  }
  __syncthreads();

  {
    int t = tid >> 2, p = tid & 3;
    const float* row = ybuf + t * 100 + p * 24;
    float s = 0.f, s2 = 0.f;
    for (int c = 0; c < 24; ++c) { float v = row[c]; s += v; s2 += v * v; }
    s += __shfl_xor(s, 1, 64); s2 += __shfl_xor(s2, 1, 64);
    s += __shfl_xor(s, 2, 64); s2 += __shfl_xor(s2, 2, 64);
    if (p == 0) {
      float mu = s * (1.f / 96.f);
      float var = s2 * (1.f / 96.f) - mu * mu;
      mu_s[t] = mu;
      rs_s[t] = rsqrtf(fmaxf(var, 0.f) + 1e-5f);
    }
  }
  __syncthreads();

  // float4 LN2 + residual epilogue
  for (int idx = tid; idx < 1536; idx += 256) {
    int t = idx / 24, c4 = (idx - t * 24) * 4;
    float mu = mu_s[t], rs = rs_s[t];
    float4 y4 = *(float4*)&ybuf[t * 100 + c4];
    float4 g4 = *(const float4*)&n2g[c4];
    float4 b4 = *(const float4*)&n2b[c4];
    float* gp = &xio[tok0 * 96 + t * 96 + c4];
    float4 x4 = *(const float4*)gp;
    float4 ov;
    ov.x = x4.x + (y4.x - mu) * rs * g4.x + b4.x;
    ov.y = x4.y + (y4.y - mu) * rs * g4.y + b4.y;
    ov.z = x4.z + (y4.z - mu) * rs * g4.z + b4.z;
    ov.w = x4.w + (y4.w - mu) * rs * g4.w + b4.w;
    *(float4*)gp = ov;
  }
}

// ---------------- launch ------------------------------------------------------
extern "C" void kernel_launch(void* const* d_in, const int* in_sizes, int n_in,
                              void* d_out, int out_size, void* d_ws, size_t ws_size,
                              hipStream_t stream) {
  const float* x           = (const float*)d_in[0];
  const float* attn_mask   = (const float*)d_in[1];
  const float* qkv_w       = (const float*)d_in[2];
  const float* q_bias      = (const float*)d_in[3];
  const float* v_bias      = (const float*)d_in[4];
  const float* logit_scale = (const float*)d_in[5];
  const float* cpb_w1      = (const float*)d_in[6];
  const float* cpb_b1      = (const float*)d_in[7];
  const float* cpb_w2      = (const float*)d_in[8];
  const float* proj_w      = (const float*)d_in[9];
  const float* proj_b      = (const float*)d_in[10];
  const float* n1g         = (const float*)d_in[11];
  const float* n1b         = (const float*)d_in[12];
  const float* fc1_w       = (const float*)d_in[13];
  const float* fc1_b       = (const float*)d_in[14];
  const float* fc2_w       = (const float*)d_in[15];
  const float* fc2_b       = (const float*)d_in[16];
  const float* n2g         = (const float*)d_in[17];
  const float* n2b         = (const float*)d_in[18];
  float* out = (float*)d_out;

  // ---- workspace layout ----
  float* tab     = (float*)d_ws;                       // 512 f32
  float* bmtab   = tab + 512;                          // 460992 f32 (1.84 MB)
  unsigned* qkvf = (unsigned*)(bmtab + 460992);        // 13824 dw
  unsigned* w1f  = qkvf + 13824;                       // 18432 dw
  unsigned* w2f  = w1f + 18432;                        // 18432 dw
  unsigned* pwf  = w2f + 18432;                        // 4608 dw
  unsigned* qws  = pwf + 4608;                         // 9,633,792 dw each
  unsigned* kws  = qws + 9633792;
  unsigned* vws  = kws + 9633792;

  wconv2_kernel<<<54, 256, 0, stream>>>(qkv_w, fc1_w, fc2_w, proj_w,
                                        qkvf, w1f, w2f, pwf);
  cpb_table_kernel<<<1, 512, 0, stream>>>(cpb_w1, cpb_b1, cpb_w2, tab);
  bm_kernel<<<(64 * NHEADS * NTOK * NTOK + 255) / 256, 256, 0, stream>>>(
      tab, attn_mask, bmtab);
  qkv_mfma_kernel<<<NTOKENS / 64, 256, 0, stream>>>(x, qkvf, q_bias, v_bias,
                                                    logit_scale, qws, kws, vws);
  attn_fused_kernel<<<NWIN_TOT, 256, 0, stream>>>(qws, kws, vws, bmtab,
                                                  pwf, proj_b, x, n1g, n1b, out);
  mlp_mfma_kernel<<<NTOKENS / 64, 256, 0, stream>>>(w1f, fc1_b, w2f, fc2_b,
                                                    n2g, n2b, out);
}